// Round 9
// baseline (69.776 us; speedup 1.0000x reference)
//
#include <hip/hip_runtime.h>

// x (64,3,512,512) f32, mean_params (64,4) f32.
#define BB 64
#define CC 3
#define HH 512
#define WW 512
#define HW (HH * WW)           // 262144
#define CHW (CC * HW)          // 786432

#define PROWS 64               // max staged rows
#define PSTRIDE 68             // LDS row stride in floats; 68 % 32 == 4 -> bank spread

typedef float f2_t __attribute__((ext_vector_type(2), aligned(4)));
typedef float f4_t __attribute__((ext_vector_type(4), aligned(16)));

// R6 skeleton (shared geometry, per-channel patch, single 17.4KB buffer,
// 8 blocks/CU) + occupancy-free pipelining:
//  - MLP staging: 4 loads in flight, then 4 ds_writes (1 exposed latency)
//  - ch+1 prefetched into REGISTERS during blend of ch (no double buffer)
//  - tight staging width BxA (only bbox columns fetched)
//  - affine coeffs inlined (no prep kernel)
__global__ __launch_bounds__(256, 8) void affine_sample_kernel(
    const float* __restrict__ x,
    const float* __restrict__ mp,
    float* __restrict__ out)
{
    __shared__ float smem[PROWS * PSTRIDE];      // 17408 B

    int tid  = threadIdx.x;
    int lane = tid & 63;
    int wid  = tid >> 6;
    int strip = lane & 7;
    int lrow  = lane >> 3;

    int bidx = blockIdx.x;          // [b:6][tile:8]
    int b    = bidx >> 8;
    int rem  = bidx & 255;
    int tileH = (rem >> 4) << 5;
    int tileW = (rem & 15) << 5;

    int h  = tileH + (wid << 3) + lrow;
    int w0 = tileW + (strip << 2);

    // ---- per-batch affine coefficients in PIXEL space (wave-uniform)
    float theta = mp[b * 4 + 0];
    float scl   = mp[b * 4 + 1];
    float tx    = mp[b * 4 + 2];
    float ty    = mp[b * 4 + 3];
    float sn, cs;
    sincosf(theta, &sn, &cs);
    float ct = scl * cs;
    float st = scl * sn;
    const float dd = -255.5f;                    // 256*xs at w=0
    float Cx = dd * (ct - st) + 256.0f * tx + 255.5f;
    float Cy = dd * (st + ct) + 256.0f * ty + 255.5f;

    // ---- block-uniform source bbox from tile corners
    float wA = (float)tileW, wB = (float)(tileW + 31);
    float hA = (float)tileH, hB = (float)(tileH + 31);
    float cwA = ct * wA, cwB = ct * wB, shA = st * hA, shB = st * hB;
    float ixmin = fminf(cwA, cwB) - fmaxf(shA, shB) + Cx;
    float ixmax = fmaxf(cwA, cwB) - fminf(shA, shB) + Cx;
    float swA = st * wA, swB = st * wB, chA = ct * hA, chB = ct * hB;
    float iymin = fminf(swA, swB) + fminf(chA, chB) + Cy;
    float iymax = fmaxf(swA, swB) + fmaxf(chA, chB) + Cy;

    int bx_lo = (int)floorf(ixmin) - 1;          // +-1: ulp-drift margin
    int bx_hi = (int)floorf(ixmax) + 2;
    int by_lo = (int)floorf(iymin) - 1;
    int by_hi = (int)floorf(iymax) + 2;
    int px_lo = min(max(bx_lo, 0), WW - 2);
    int px_hi = min(max(bx_hi - 1, 0), WW - 2) + 1;
    int py_lo = min(max(by_lo, 0), HH - 2);
    int py_hi = min(max(by_hi - 1, 0), HH - 2) + 1;
    int By = py_hi - py_lo + 1;

    int ax_lo = px_lo & ~3;                      // 16B-aligned window start
    int span  = px_hi - ax_lo;                   // cols needed minus 1
    bool staged = (span <= 63) && (By <= PROWS);
    int BxA = (span | 3) + 1;                    // tight width, mult of 4, <=64
    if (ax_lo + BxA > WW) ax_lo = WW - BxA;      // keep window in-bounds (aligned)

    const float* plane0 = x + b * CHW;
    const float* srcb   = plane0 + py_lo * WW + ax_lo;

    int r0 = tid >> 4;                           // 0..15 staging row
    int c4 = (tid & 15) << 2;                    // 0,4,...,60 staging col

    // ---- issue ch0 staging loads EARLY (hide under geometry VALU)
    f4_t t0 = {0,0,0,0}, t1 = {0,0,0,0}, t2 = {0,0,0,0}, t3 = {0,0,0,0};
    bool g0 = false, g1 = false, g2 = false, g3 = false;
    if (staged) {
        bool cok = c4 < BxA;                     // tight width: skip unused cols
        g0 = cok & (r0      < By);
        g1 = cok & (r0 + 16 < By);
        g2 = cok & (r0 + 32 < By);
        g3 = cok & (r0 + 48 < By);
        if (g0) t0 = *(const f4_t*)(srcb +  r0       * WW + c4);
        if (g1) t1 = *(const f4_t*)(srcb + (r0 + 16) * WW + c4);
        if (g2) t2 = *(const f4_t*)(srcb + (r0 + 32) * WW + c4);
        if (g3) t3 = *(const f4_t*)(srcb + (r0 + 48) * WW + c4);
    }

    // ---- per-pixel geometry (incremental along the 4-px strip; shared by 3 ch)
    float ix = ct * (float)w0 - st * (float)h + Cx;
    float iy = st * (float)w0 + ct * (float)h + Cy;

    float al[4], ar[4], f0[4], f1[4];
    int o0[4], o1[4];
#pragma unroll
    for (int p = 0; p < 4; ++p) {
        float x0f = floorf(ix), y0f = floorf(iy);
        float fx = ix - x0f,    fy = iy - y0f;
        int x0 = (int)x0f, y0 = (int)y0f;
        int y1 = y0 + 1;

        bool xin = (x0 >= 0) & (x0 <= WW - 2);
        float wl = 1.0f - fx;
        al[p] = xin ? wl : ((x0 == -1)     ? fx : 0.0f);
        ar[p] = xin ? fx : ((x0 == WW - 1) ? wl : 0.0f);
        int base = min(max(x0, 0), WW - 2);

        bool vy0 = (y0 >= 0) & (y0 < HH);
        bool vy1 = (y1 >= 0) & (y1 < HH);
        int y0c = min(max(y0, 0), HH - 1);
        int y1c = min(max(y1, 0), HH - 1);
        f0[p] = (1.0f - fy) * (float)vy0;
        f1[p] = fy          * (float)vy1;

        if (staged) {
            int lx = base - ax_lo;               // in [0, BxA-2]
            o0[p] = (y0c - py_lo) * PSTRIDE + lx;
            o1[p] = (y1c - py_lo) * PSTRIDE + lx;
        } else {
            o0[p] = y0c * WW + base;
            o1[p] = y1c * WW + base;
        }
        ix += ct;
        iy += st;
    }

    float* ob = out + b * CHW + h * WW + w0;

    if (staged) {
        // drain ch0 regs -> LDS (loads completed during geometry)
        if (g0) *(f4_t*)(&smem[ r0       * PSTRIDE + c4]) = t0;
        if (g1) *(f4_t*)(&smem[(r0 + 16) * PSTRIDE + c4]) = t1;
        if (g2) *(f4_t*)(&smem[(r0 + 32) * PSTRIDE + c4]) = t2;
        if (g3) *(f4_t*)(&smem[(r0 + 48) * PSTRIDE + c4]) = t3;
        __syncthreads();                         // patch ch0 ready

#pragma unroll
        for (int ch = 0; ch < CC; ++ch) {
            // prefetch ch+1 into regs; HBM latency hides under this blend
            if (ch < 2) {
                const float* srcn = srcb + (ch + 1) * HW;
                if (g0) t0 = *(const f4_t*)(srcn +  r0       * WW + c4);
                if (g1) t1 = *(const f4_t*)(srcn + (r0 + 16) * WW + c4);
                if (g2) t2 = *(const f4_t*)(srcn + (r0 + 32) * WW + c4);
                if (g3) t3 = *(const f4_t*)(srcn + (r0 + 48) * WW + c4);
            }

            f4_t v;
#pragma unroll
            for (int p = 0; p < 4; ++p) {
                float a0 = smem[o0[p]], a1 = smem[o0[p] + 1];
                float b0 = smem[o1[p]], b1 = smem[o1[p] + 1];
                v[p] = f0[p] * (al[p] * a0 + ar[p] * a1)
                     + f1[p] * (al[p] * b0 + ar[p] * b1);
            }
            __builtin_nontemporal_store(v, (f4_t*)(ob + ch * HW));

            if (ch < 2) {
                __syncthreads();                 // all blends of ch done
                if (g0) *(f4_t*)(&smem[ r0       * PSTRIDE + c4]) = t0;
                if (g1) *(f4_t*)(&smem[(r0 + 16) * PSTRIDE + c4]) = t1;
                if (g2) *(f4_t*)(&smem[(r0 + 32) * PSTRIDE + c4]) = t2;
                if (g3) *(f4_t*)(&smem[(r0 + 48) * PSTRIDE + c4]) = t3;
                __syncthreads();                 // patch ch+1 ready
            }
        }
    } else {
        // fallback: direct global f2 gathers (block-uniform branch, no barriers)
#pragma unroll
        for (int ch = 0; ch < CC; ++ch) {
            const float* pl = plane0 + ch * HW;
            f4_t v;
#pragma unroll
            for (int p = 0; p < 4; ++p) {
                f2_t t = *(const f2_t*)(pl + o0[p]);
                f2_t u = *(const f2_t*)(pl + o1[p]);
                v[p] = f0[p] * (al[p] * t.x + ar[p] * t.y)
                     + f1[p] * (al[p] * u.x + ar[p] * u.y);
            }
            __builtin_nontemporal_store(v, (f4_t*)(ob + ch * HW));
        }
    }
}

extern "C" void kernel_launch(void* const* d_in, const int* in_sizes, int n_in,
                              void* d_out, int out_size, void* d_ws, size_t ws_size,
                              hipStream_t stream)
{
    const float* x  = (const float*)d_in[0];
    const float* mp = (const float*)d_in[1];
    float* out = (float*)d_out;

    dim3 block(256);
    dim3 grid(BB * 256);            // 64 batches x 16x16 tiles of 32x32
    affine_sample_kernel<<<grid, block, 0, stream>>>(x, mp, out);
}